// Round 9
// baseline (186.342 us; speedup 1.0000x reference)
//
#include <hip/hip_runtime.h>
#include <cstddef>

typedef __attribute__((ext_vector_type(8))) short short8;
typedef __attribute__((ext_vector_type(4))) float f32x4;

constexpr int CL = 32;    // scan chunk length

__device__ inline ushort tobf(float f) {
  union { float f; unsigned u; } v; v.f = f;
  return (ushort)((v.u + 0x7FFFu + ((v.u >> 16) & 1u)) >> 16);
}
__device__ inline float frombf(ushort u) {
  union { unsigned u; float f; } v; v.u = ((unsigned)u) << 16; return v.f;
}

// ---------------- prep: bf16 weight transposes, x cast, sel/sums/out init ---
__global__ __launch_bounds__(256)
void prep(const float* __restrict__ Wemb, const float* __restrict__ Wxp,
          const float* __restrict__ Wout, const float* __restrict__ x,
          const float* __restrict__ bxp, const float* __restrict__ bout,
          ushort* __restrict__ WembT, ushort* __restrict__ wBCdT,
          ushort* __restrict__ WoutT, ushort* __restrict__ xbf,
          float* __restrict__ sel, float* __restrict__ sums,
          float* __restrict__ out) {
  int idx = blockIdx.x * 256 + threadIdx.x;
  if (idx < 131072) {                        // WembT[n][k] = Wemb[k][n], K=128
    int n = idx >> 7, k = idx & 127;
    WembT[idx] = tobf(Wemb[k * 1024 + n]);
  } else if (idx < 327680) {                 // wBCdT[n][k]; n<128 BC, 128 wd, else 0
    int j = idx - 131072;
    int n = j >> 10, k = j & 1023;
    float v = (n < 128) ? Wxp[k * 129 + 1 + n] : (n == 128 ? Wxp[k * 129] : 0.f);
    wBCdT[j] = tobf(v);
  } else if (idx < 458752) {                 // WoutT[n][k] = Wout[k][n], K=1024
    int j = idx - 327680;
    int n = j >> 10, k = j & 1023;
    WoutT[j] = tobf(Wout[k * 128 + n]);
  } else if (idx < 720896) {                 // x -> bf16
    int j = idx - 458752;
    xbf[j] = tobf(x[j]);
  } else if (idx < 1114112) {                // sel <- bias (rows of 192)
    int j = idx - 720896;
    int c = j % 192;
    sel[j] = (c < 128) ? bxp[1 + c] : (c == 128 ? bxp[0] : 0.f);
  } else if (idx < 1118208) {                // sums <- 0 (s1[2048] + s2[2048])
    sums[idx - 1114112] = 0.f;
  } else if (idx < 1380352) {                // out <- bout
    int j = idx - 1118208;
    out[j] = bout[j & 127];
  }
}

// ---------------- bf16 MFMA GEMM: A[M][K], BT[N][K], 64x64 tile -------------
// MODE 0: Cbf = tobf(acc + bias[gn]), full K.     (G1)
// MODE 1: atomicAdd(&Cf[...], acc), K-slice blockIdx.z. (G2 split-K)
// XOR-swizzle applied to FULL final byte offset on both sides (rule #21).
template<int MODE>
__global__ __launch_bounds__(256)
void gemm_bt(const ushort* __restrict__ A, const ushort* __restrict__ BT,
             const float* __restrict__ bias, float* __restrict__ Cf,
             ushort* __restrict__ Cbf, int M, int N, int K, int kchunk) {
  __shared__ __align__(16) ushort sA[8192];   // [64 rows][128 k] swizzled
  __shared__ __align__(16) ushort sB[8192];
  const int t  = threadIdx.x;
  const int n0 = blockIdx.x * 64;
  const int m0 = blockIdx.y * 64;
  const int k0 = (MODE == 1) ? blockIdx.z * kchunk : 0;
  const int k1 = (MODE == 1) ? k0 + kchunk : K;

  const int lane = t & 63, w = t >> 6;
  const int wr = w << 4;
  const int colsel = lane & 15;
  const int kg = lane >> 4;

  f32x4 acc[4];
  #pragma unroll
  for (int nf = 0; nf < 4; ++nf) acc[nf] = (f32x4)(0.f);

  for (int kc = k0; kc < k1; kc += 128) {
    __syncthreads();
    #pragma unroll
    for (int i = 0; i < 4; ++i) {
      int c = t + (i << 8);
      int row = c >> 4, kk = (c & 15) << 3;
      float4 va  = *(const float4*)(A  + (size_t)(m0 + row) * K + kc + kk);
      float4 vb4 = *(const float4*)(BT + (size_t)(n0 + row) * K + kc + kk);
      int byteoff = ((row << 8) + (kk << 1)) ^ ((row & 7) << 4);
      *(float4*)((char*)sA + byteoff) = va;
      *(float4*)((char*)sB + byteoff) = vb4;
    }
    __syncthreads();
    short8 a[4];
    {
      int arow = wr + colsel;
      int lin = (arow << 8) + (kg << 4);
      int swz = (arow & 7) << 4;
      #pragma unroll
      for (int ks = 0; ks < 4; ++ks)
        a[ks] = *(const short8*)((const char*)sA + ((lin + (ks << 6)) ^ swz));
    }
    #pragma unroll
    for (int nf = 0; nf < 4; ++nf) {
      int brow = (nf << 4) + colsel;
      int lin = (brow << 8) + (kg << 4);
      int swz = (brow & 7) << 4;
      #pragma unroll
      for (int ks = 0; ks < 4; ++ks) {
        short8 b = *(const short8*)((const char*)sB + ((lin + (ks << 6)) ^ swz));
        acc[nf] = __builtin_amdgcn_mfma_f32_16x16x32_bf16(a[ks], b, acc[nf], 0, 0, 0);
      }
    }
  }
  // D layout: col=lane&15, row=(lane>>4)*4+reg  [m89]
  const int r4 = kg << 2;
  #pragma unroll
  for (int nf = 0; nf < 4; ++nf) {
    int gn = n0 + (nf << 4) + colsel;
    #pragma unroll
    for (int reg = 0; reg < 4; ++reg) {
      int gm = m0 + wr + r4 + reg;
      if (MODE == 0) {
        Cbf[(size_t)gm * N + gn] = tobf(acc[nf][reg] + bias[gn]);
      } else {
        atomicAdd(&Cf[(size_t)gm * N + gn], acc[nf][reg]);
      }
    }
  }
}

// ---------------- G4 with inline LayerNorm in A-staging ---------------------
// A = ybf (bf16, un-normalized); per-row (mean,rstd) from sums; gamma/beta
// applied during staging. M=2048,N=128,K=1024, split-K=4 via atomics into out.
__global__ __launch_bounds__(256)
void gemm_ln(const ushort* __restrict__ ybf, const ushort* __restrict__ BT,
             const float* __restrict__ sums, const float* __restrict__ gamma,
             const float* __restrict__ beta, float* __restrict__ out) {
  __shared__ __align__(16) ushort sA[8192];
  __shared__ __align__(16) ushort sB[8192];
  __shared__ float sLN[128];               // [row]{mean,rstd}
  const int t  = threadIdx.x;
  const int n0 = blockIdx.x * 64;
  const int m0 = blockIdx.y * 64;
  const int k0 = blockIdx.z * 256;
  const int k1 = k0 + 256;

  if (t < 64) {
    float s1 = sums[m0 + t], s2 = sums[2048 + m0 + t];
    float mean = s1 * (1.f / 1024.f);
    float var  = s2 * (1.f / 1024.f) - mean * mean;
    sLN[2 * t] = mean;
    sLN[2 * t + 1] = rsqrtf(var + 1e-5f);
  }

  const int lane = t & 63, w = t >> 6;
  const int wr = w << 4;
  const int colsel = lane & 15;
  const int kg = lane >> 4;
  const int kk_t = (t & 15) << 3;          // this thread's fixed k-offset

  f32x4 acc[4];
  #pragma unroll
  for (int nf = 0; nf < 4; ++nf) acc[nf] = (f32x4)(0.f);

  for (int kc = k0; kc < k1; kc += 128) {
    float4 g0 = *(const float4*)&gamma[kc + kk_t];
    float4 g1 = *(const float4*)&gamma[kc + kk_t + 4];
    float4 be0 = *(const float4*)&beta[kc + kk_t];
    float4 be1 = *(const float4*)&beta[kc + kk_t + 4];
    float gv[8] = {g0.x, g0.y, g0.z, g0.w, g1.x, g1.y, g1.z, g1.w};
    float bv[8] = {be0.x, be0.y, be0.z, be0.w, be1.x, be1.y, be1.z, be1.w};
    __syncthreads();
    #pragma unroll
    for (int i = 0; i < 4; ++i) {
      int c = t + (i << 8);
      int row = c >> 4, kk = (c & 15) << 3;
      short8 ya = *(const short8*)(ybf + (size_t)(m0 + row) * 1024 + kc + kk);
      float4 vb4 = *(const float4*)(BT + (size_t)(n0 + row) * 1024 + kc + kk);
      float mean = sLN[2 * row], rstd = sLN[2 * row + 1];
      short8 na;
      #pragma unroll
      for (int j = 0; j < 8; ++j) {
        float yv = frombf((ushort)ya[j]);
        na[j] = (short)tobf((yv - mean) * rstd * gv[j] + bv[j]);
      }
      int byteoff = ((row << 8) + (kk << 1)) ^ ((row & 7) << 4);
      *(short8*)((char*)sA + byteoff) = na;
      *(float4*)((char*)sB + byteoff) = vb4;
    }
    __syncthreads();
    short8 a[4];
    {
      int arow = wr + colsel;
      int lin = (arow << 8) + (kg << 4);
      int swz = (arow & 7) << 4;
      #pragma unroll
      for (int ks = 0; ks < 4; ++ks)
        a[ks] = *(const short8*)((const char*)sA + ((lin + (ks << 6)) ^ swz));
    }
    #pragma unroll
    for (int nf = 0; nf < 4; ++nf) {
      int brow = (nf << 4) + colsel;
      int lin = (brow << 8) + (kg << 4);
      int swz = (brow & 7) << 4;
      #pragma unroll
      for (int ks = 0; ks < 4; ++ks) {
        short8 b = *(const short8*)((const char*)sB + ((lin + (ks << 6)) ^ swz));
        acc[nf] = __builtin_amdgcn_mfma_f32_16x16x32_bf16(a[ks], b, acc[nf], 0, 0, 0);
      }
    }
  }
  const int r4 = kg << 2;
  #pragma unroll
  for (int nf = 0; nf < 4; ++nf) {
    int gn = n0 + (nf << 4) + colsel;
    #pragma unroll
    for (int reg = 0; reg < 4; ++reg) {
      int gm = m0 + wr + r4 + reg;
      atomicAdd(&out[(size_t)gm * 128 + gn], acc[nf][reg]);
    }
  }
}

// ---- in-LDS sel->abc transform (wave-synchronous, one wave per row) --------
__device__ __forceinline__ void transform_sbuf(float* sbuf, float a_d, int t) {
  const int d = t & 63;
  #pragma unroll
  for (int i = 0; i < 8; ++i) {
    float* R = sbuf + ((t >> 6) + i * 4) * 192;
    float draw = R[128];
    float sp = (draw > 15.f) ? draw : log1pf(__expf(draw));
    float delta = 0.01f * sp;
    R[d] = delta * R[d];
    R[128 + d] = __expf(delta * a_d);
  }
}

// ============================================================================
// Chunked scan (3 phases). lane = m, all 64 d in registers.
// sbuf after transform: B_bar=[0:64], C=[64:128], A_bar=[128:192].
// ============================================================================
__global__ __launch_bounds__(256)
void scan_sum(const ushort* __restrict__ ubf, const float* __restrict__ sel,
              const float* __restrict__ A,
              float* __restrict__ cst, float* __restrict__ Ach) {
  __shared__ __align__(16) float sbuf[CL * 192];
  const int t = threadIdx.x, lane = t & 63, w = t >> 6;
  const int tc = blockIdx.x % 15;
  const int mg = (blockIdx.x / 15) & 3;
  const int b  = blockIdx.x / 60;
  const int r0 = b * 512 + tc * CL;

  const float a_d = A[t & 63];
  const float4* src = (const float4*)(sel + (size_t)r0 * 192);
  #pragma unroll
  for (int i = 0; i < 6; ++i)
    ((float4*)sbuf)[t + i * 256] = src[t + i * 256];
  __syncthreads();
  transform_sbuf(sbuf, a_d, t);
  __syncthreads();

  const int m = (mg * 4 + w) * 64 + lane;
  const ushort* ub = ubf + (size_t)r0 * 1024 + m;
  const bool doAp = (mg == 0 && w == 0);

  float2 h[32], ap[32];
  #pragma unroll
  for (int j = 0; j < 32; ++j) { h[j] = make_float2(0.f, 0.f); ap[j] = make_float2(1.f, 1.f); }

  float u0 = frombf(ub[0]);
  float u1 = frombf(ub[1024]);
  for (int s = 0; s < CL; ++s) {
    int sn = (s < CL - 3) ? s + 2 : CL - 1;
    float u2 = frombf(ub[(size_t)sn * 1024]);
    const float* L = sbuf + s * 192;
    #pragma unroll
    for (int jj = 0; jj < 16; ++jj) {
      float4 a4 = *(const float4*)&L[128 + 4 * jj];
      float4 b4 = *(const float4*)&L[4 * jj];
      h[2 * jj].x     = fmaf(h[2 * jj].x,     a4.x, b4.x * u0);
      h[2 * jj].y     = fmaf(h[2 * jj].y,     a4.y, b4.y * u0);
      h[2 * jj + 1].x = fmaf(h[2 * jj + 1].x, a4.z, b4.z * u0);
      h[2 * jj + 1].y = fmaf(h[2 * jj + 1].y, a4.w, b4.w * u0);
    }
    if (doAp) {
      #pragma unroll
      for (int jj = 0; jj < 16; ++jj) {
        float4 a4 = *(const float4*)&L[128 + 4 * jj];
        ap[2 * jj].x     *= a4.x;
        ap[2 * jj].y     *= a4.y;
        ap[2 * jj + 1].x *= a4.z;
        ap[2 * jj + 1].y *= a4.w;
      }
    }
    u0 = u1; u1 = u2;
  }

  size_t cbase = (((size_t)b * 15 + tc) * 64) * 1024 + m;
  #pragma unroll
  for (int j = 0; j < 32; ++j) {
    cst[cbase + (size_t)(2 * j)     * 1024] = h[j].x;
    cst[cbase + (size_t)(2 * j + 1) * 1024] = h[j].y;
  }
  if (doAp && lane == 0) {
    float2* ad = (float2*)&Ach[((size_t)b * 15 + tc) * 64];
    #pragma unroll
    for (int j = 0; j < 32; ++j) ad[j] = ap[j];
  }
}

__global__ __launch_bounds__(256)
void scan_comb(float* __restrict__ cst, const float* __restrict__ Ach) {
  int g = blockIdx.x * 256 + threadIdx.x;  // 0..262143
  int b = g >> 16;
  int rem = g & 65535;
  int d = rem >> 10;
  int m = rem & 1023;
  float h = 0.f;
  for (int t2 = 0; t2 < 15; ++t2) {
    size_t idx = (((size_t)(b * 15 + t2)) * 64 + d) * 1024 + m;
    h = fmaf(Ach[(b * 15 + t2) * 64 + d], h, cst[idx]);
    cst[idx] = h;
  }
}

// ---- scan_out: emit y as bf16 + per-row (sum, sumsq) via wave-reduce -------
__global__ __launch_bounds__(256)
void scan_out(const ushort* __restrict__ ubf, const float* __restrict__ sel,
              const float* __restrict__ A, const float* __restrict__ cst,
              const float* __restrict__ Dp, ushort* __restrict__ ybf,
              float* __restrict__ sums) {
  __shared__ __align__(16) float sbuf[CL * 192];
  const int t = threadIdx.x, lane = t & 63, w = t >> 6;
  const int tc = blockIdx.x & 15;
  const int mg = (blockIdx.x >> 4) & 3;
  const int b  = blockIdx.x >> 6;
  const int r0 = b * 512 + tc * CL;

  const float a_d = A[t & 63];
  const float4* src = (const float4*)(sel + (size_t)r0 * 192);
  #pragma unroll
  for (int i = 0; i < 6; ++i)
    ((float4*)sbuf)[t + i * 256] = src[t + i * 256];
  __syncthreads();
  transform_sbuf(sbuf, a_d, t);
  __syncthreads();

  const int m = (mg * 4 + w) * 64 + lane;
  const ushort* ub = ubf + (size_t)r0 * 1024 + m;
  ushort* yb = ybf + (size_t)r0 * 1024 + m;
  const float dp = Dp[m];

  float2 h[32];
  if (tc == 0) {
    #pragma unroll
    for (int j = 0; j < 32; ++j) h[j] = make_float2(0.f, 0.f);
  } else {
    size_t cbase = (((size_t)b * 15 + (tc - 1)) * 64) * 1024 + m;
    #pragma unroll
    for (int j = 0; j < 32; ++j) {
      h[j].x = cst[cbase + (size_t)(2 * j)     * 1024];
      h[j].y = cst[cbase + (size_t)(2 * j + 1) * 1024];
    }
  }

  float u0 = frombf(ub[0]);
  float u1 = frombf(ub[1024]);
  for (int s = 0; s < CL; ++s) {
    int sn = (s < CL - 3) ? s + 2 : CL - 1;
    float u2 = frombf(ub[(size_t)sn * 1024]);
    const float* L = sbuf + s * 192;
    float y0 = 0.f, y1 = 0.f, y2 = 0.f, y3 = 0.f;
    #pragma unroll
    for (int jj = 0; jj < 16; ++jj) {
      float4 a4 = *(const float4*)&L[128 + 4 * jj];
      float4 b4 = *(const float4*)&L[4 * jj];
      float4 c4 = *(const float4*)&L[64 + 4 * jj];
      h[2 * jj].x     = fmaf(h[2 * jj].x,     a4.x, b4.x * u0);
      h[2 * jj].y     = fmaf(h[2 * jj].y,     a4.y, b4.y * u0);
      h[2 * jj + 1].x = fmaf(h[2 * jj + 1].x, a4.z, b4.z * u0);
      h[2 * jj + 1].y = fmaf(h[2 * jj + 1].y, a4.w, b4.w * u0);
      y0 = fmaf(c4.x, h[2 * jj].x,     y0);
      y1 = fmaf(c4.y, h[2 * jj].y,     y1);
      y2 = fmaf(c4.z, h[2 * jj + 1].x, y2);
      y3 = fmaf(c4.w, h[2 * jj + 1].y, y3);
    }
    float yv = (y0 + y1) + (y2 + y3) + u0 * dp;
    yb[(size_t)s * 1024] = tobf(yv);
    // wave-reduce (lanes of this wave share token-row r0+s)
    float rs1 = yv, rs2 = yv * yv;
    #pragma unroll
    for (int o = 32; o; o >>= 1) {
      rs1 += __shfl_xor(rs1, o, 64);
      rs2 += __shfl_xor(rs2, o, 64);
    }
    if (lane == 0) {
      atomicAdd(&sums[r0 + s], rs1);
      atomicAdd(&sums[2048 + r0 + s], rs2);
    }
    u0 = u1; u1 = u2;
  }
}

extern "C" void kernel_launch(void* const* d_in, const int* in_sizes, int n_in,
                              void* d_out, int out_size, void* d_ws, size_t ws_size,
                              hipStream_t stream) {
  const float* x     = (const float*)d_in[0];
  const float* Wemb  = (const float*)d_in[1];
  const float* bemb  = (const float*)d_in[2];
  const float* Wxp   = (const float*)d_in[3];
  const float* bxp   = (const float*)d_in[4];
  const float* A     = (const float*)d_in[5];
  const float* Dp    = (const float*)d_in[6];
  const float* gamma = (const float*)d_in[7];
  const float* beta  = (const float*)d_in[8];
  const float* Wout  = (const float*)d_in[9];
  const float* bout  = (const float*)d_in[10];
  float* out = (float*)d_out;
  float* ws  = (float*)d_ws;

  // ws layout (floats)
  float* sel  = ws;                         //   393,216
  float* cst  = ws + 393216;                // 3,932,160
  float* Ach  = ws + 4325376;               //     4,096
  float* sums = ws + 4329472;               //     4,096 (s1|s2)
  ushort* ubf   = (ushort*)(ws + 4333568);  // 2,097,152 us
  ushort* ybf   = ubf + 2097152;            // 2,097,152 us
  ushort* xbf   = ybf + 2097152;            //   262,144 us
  ushort* WembT = xbf + 262144;             //   131,072 us
  ushort* wBCdT = WembT + 131072;           //   196,608 us
  ushort* WoutT = wBCdT + 196608;           //   131,072 us

  // P0: prep (transposes + x cast + sel/sums/out init)
  prep<<<5392, 256, 0, stream>>>(Wemb, Wxp, Wout, x, bxp, bout,
                                 WembT, wBCdT, WoutT, xbf, sel, sums, out);
  // P1: G1  ubf = bf16(x @ Wemb + bemb)
  gemm_bt<0><<<dim3(16, 32, 1), 256, 0, stream>>>(
      xbf, WembT, bemb, nullptr, ubf, 2048, 1024, 128, 0);
  // P2: G2  sel += ubf @ wBCdT^T  (split-K=4, atomics)
  gemm_bt<1><<<dim3(3, 32, 4), 256, 0, stream>>>(
      ubf, wBCdT, nullptr, sel, nullptr, 2048, 192, 1024, 256);
  // P3-P5: chunked scan; scan_out emits bf16 y + LN sums
  scan_sum<<<240, 256, 0, stream>>>(ubf, sel, A, cst, Ach);
  scan_comb<<<1024, 256, 0, stream>>>(cst, Ach);
  scan_out<<<256, 256, 0, stream>>>(ubf, sel, A, cst, Dp, ybf, sums);
  // P6: G4 with inline LN  out += LN(y) @ WoutT^T  (split-K=4, atomics)
  gemm_ln<<<dim3(2, 32, 4), 256, 0, stream>>>(
      ybf, WoutT, sums, gamma, beta, out);
}

// Round 10
// 165.600 us; speedup vs baseline: 1.1253x; 1.1253x over previous
//
#include <hip/hip_runtime.h>
#include <cstddef>

typedef __attribute__((ext_vector_type(8))) short short8;
typedef __attribute__((ext_vector_type(4))) float f32x4;

constexpr int CL  = 16;   // scan chunk length
constexpr int NTC = 32;   // time chunks (NTC*CL == 512)
constexpr int NC1 = 31;   // stored chunk states (NTC-1)

__device__ inline ushort tobf(float f) {
  union { float f; unsigned u; } v; v.f = f;
  return (ushort)((v.u + 0x7FFFu + ((v.u >> 16) & 1u)) >> 16);
}
__device__ inline float frombf(ushort u) {
  union { unsigned u; float f; } v; v.u = ((unsigned)u) << 16; return v.f;
}

// ---------------- prep: bf16 weight transposes, x cast, sel/sums/out init ---
__global__ __launch_bounds__(256)
void prep(const float* __restrict__ Wemb, const float* __restrict__ Wxp,
          const float* __restrict__ Wout, const float* __restrict__ x,
          const float* __restrict__ bxp, const float* __restrict__ bout,
          ushort* __restrict__ WembT, ushort* __restrict__ wBCdT,
          ushort* __restrict__ WoutT, ushort* __restrict__ xbf,
          float* __restrict__ sel, float* __restrict__ sums,
          float* __restrict__ out) {
  int idx = blockIdx.x * 256 + threadIdx.x;
  if (idx < 131072) {                        // WembT[n][k] = Wemb[k][n], K=128
    int n = idx >> 7, k = idx & 127;
    WembT[idx] = tobf(Wemb[k * 1024 + n]);
  } else if (idx < 327680) {                 // wBCdT[n][k]; n<128 BC, 128 wd, else 0
    int j = idx - 131072;
    int n = j >> 10, k = j & 1023;
    float v = (n < 128) ? Wxp[k * 129 + 1 + n] : (n == 128 ? Wxp[k * 129] : 0.f);
    wBCdT[j] = tobf(v);
  } else if (idx < 458752) {                 // WoutT[n][k] = Wout[k][n], K=1024
    int j = idx - 327680;
    int n = j >> 10, k = j & 1023;
    WoutT[j] = tobf(Wout[k * 128 + n]);
  } else if (idx < 720896) {                 // x -> bf16
    int j = idx - 458752;
    xbf[j] = tobf(x[j]);
  } else if (idx < 1114112) {                // sel <- bias (rows of 192)
    int j = idx - 720896;
    int c = j % 192;
    sel[j] = (c < 128) ? bxp[1 + c] : (c == 128 ? bxp[0] : 0.f);
  } else if (idx < 1118208) {                // sums <- 0 (s1[2048] | s2[2048])
    sums[idx - 1114112] = 0.f;
  } else if (idx < 1380352) {                // out <- bout
    int j = idx - 1118208;
    out[j] = bout[j & 127];
  }
}

// ---------------- bf16 MFMA GEMM: A[M][K], BT[N][K], 64x64 tile -------------
// MODE 0: Cbf = tobf(acc + bias[gn]), full K.     (G1)
// MODE 1: atomicAdd(&Cf[...], acc), K-slice blockIdx.z. (G2 split-K)
// XOR-swizzle applied to FULL final byte offset on both sides (rule #21).
template<int MODE>
__global__ __launch_bounds__(256)
void gemm_bt(const ushort* __restrict__ A, const ushort* __restrict__ BT,
             const float* __restrict__ bias, float* __restrict__ Cf,
             ushort* __restrict__ Cbf, int M, int N, int K, int kchunk) {
  __shared__ __align__(16) ushort sA[8192];   // [64 rows][128 k] swizzled
  __shared__ __align__(16) ushort sB[8192];
  const int t  = threadIdx.x;
  const int n0 = blockIdx.x * 64;
  const int m0 = blockIdx.y * 64;
  const int k0 = (MODE == 1) ? blockIdx.z * kchunk : 0;
  const int k1 = (MODE == 1) ? k0 + kchunk : K;

  const int lane = t & 63, w = t >> 6;
  const int wr = w << 4;
  const int colsel = lane & 15;
  const int kg = lane >> 4;

  f32x4 acc[4];
  #pragma unroll
  for (int nf = 0; nf < 4; ++nf) acc[nf] = (f32x4)(0.f);

  for (int kc = k0; kc < k1; kc += 128) {
    __syncthreads();
    #pragma unroll
    for (int i = 0; i < 4; ++i) {
      int c = t + (i << 8);
      int row = c >> 4, kk = (c & 15) << 3;
      float4 va  = *(const float4*)(A  + (size_t)(m0 + row) * K + kc + kk);
      float4 vb4 = *(const float4*)(BT + (size_t)(n0 + row) * K + kc + kk);
      int byteoff = ((row << 8) + (kk << 1)) ^ ((row & 7) << 4);
      *(float4*)((char*)sA + byteoff) = va;
      *(float4*)((char*)sB + byteoff) = vb4;
    }
    __syncthreads();
    short8 a[4];
    {
      int arow = wr + colsel;
      int lin = (arow << 8) + (kg << 4);
      int swz = (arow & 7) << 4;
      #pragma unroll
      for (int ks = 0; ks < 4; ++ks)
        a[ks] = *(const short8*)((const char*)sA + ((lin + (ks << 6)) ^ swz));
    }
    #pragma unroll
    for (int nf = 0; nf < 4; ++nf) {
      int brow = (nf << 4) + colsel;
      int lin = (brow << 8) + (kg << 4);
      int swz = (brow & 7) << 4;
      #pragma unroll
      for (int ks = 0; ks < 4; ++ks) {
        short8 b = *(const short8*)((const char*)sB + ((lin + (ks << 6)) ^ swz));
        acc[nf] = __builtin_amdgcn_mfma_f32_16x16x32_bf16(a[ks], b, acc[nf], 0, 0, 0);
      }
    }
  }
  // D layout: col=lane&15, row=(lane>>4)*4+reg  [m89]
  const int r4 = kg << 2;
  #pragma unroll
  for (int nf = 0; nf < 4; ++nf) {
    int gn = n0 + (nf << 4) + colsel;
    #pragma unroll
    for (int reg = 0; reg < 4; ++reg) {
      int gm = m0 + wr + r4 + reg;
      if (MODE == 0) {
        Cbf[(size_t)gm * N + gn] = tobf(acc[nf][reg] + bias[gn]);
      } else {
        atomicAdd(&Cf[(size_t)gm * N + gn], acc[nf][reg]);
      }
    }
  }
}

// ---------------- G4 with inline LayerNorm in A-staging ---------------------
__global__ __launch_bounds__(256)
void gemm_ln(const ushort* __restrict__ ybf, const ushort* __restrict__ BT,
             const float* __restrict__ sums, const float* __restrict__ gamma,
             const float* __restrict__ beta, float* __restrict__ out) {
  __shared__ __align__(16) ushort sA[8192];
  __shared__ __align__(16) ushort sB[8192];
  __shared__ float sLN[128];               // [row]{mean,rstd}
  const int t  = threadIdx.x;
  const int n0 = blockIdx.x * 64;
  const int m0 = blockIdx.y * 64;
  const int k0 = blockIdx.z * 256;
  const int k1 = k0 + 256;

  if (t < 64) {
    float s1 = sums[m0 + t], s2 = sums[2048 + m0 + t];
    float mean = s1 * (1.f / 1024.f);
    float var  = s2 * (1.f / 1024.f) - mean * mean;
    sLN[2 * t] = mean;
    sLN[2 * t + 1] = rsqrtf(var + 1e-5f);
  }

  const int lane = t & 63, w = t >> 6;
  const int wr = w << 4;
  const int colsel = lane & 15;
  const int kg = lane >> 4;
  const int kk_t = (t & 15) << 3;

  f32x4 acc[4];
  #pragma unroll
  for (int nf = 0; nf < 4; ++nf) acc[nf] = (f32x4)(0.f);

  for (int kc = k0; kc < k1; kc += 128) {
    float4 g0 = *(const float4*)&gamma[kc + kk_t];
    float4 g1 = *(const float4*)&gamma[kc + kk_t + 4];
    float4 be0 = *(const float4*)&beta[kc + kk_t];
    float4 be1 = *(const float4*)&beta[kc + kk_t + 4];
    float gv[8] = {g0.x, g0.y, g0.z, g0.w, g1.x, g1.y, g1.z, g1.w};
    float bv[8] = {be0.x, be0.y, be0.z, be0.w, be1.x, be1.y, be1.z, be1.w};
    __syncthreads();
    #pragma unroll
    for (int i = 0; i < 4; ++i) {
      int c = t + (i << 8);
      int row = c >> 4, kk = (c & 15) << 3;
      short8 ya = *(const short8*)(ybf + (size_t)(m0 + row) * 1024 + kc + kk);
      float4 vb4 = *(const float4*)(BT + (size_t)(n0 + row) * 1024 + kc + kk);
      float mean = sLN[2 * row], rstd = sLN[2 * row + 1];
      short8 na;
      #pragma unroll
      for (int j = 0; j < 8; ++j) {
        float yv = frombf((ushort)ya[j]);
        na[j] = (short)tobf((yv - mean) * rstd * gv[j] + bv[j]);
      }
      int byteoff = ((row << 8) + (kk << 1)) ^ ((row & 7) << 4);
      *(short8*)((char*)sA + byteoff) = na;
      *(float4*)((char*)sB + byteoff) = vb4;
    }
    __syncthreads();
    short8 a[4];
    {
      int arow = wr + colsel;
      int lin = (arow << 8) + (kg << 4);
      int swz = (arow & 7) << 4;
      #pragma unroll
      for (int ks = 0; ks < 4; ++ks)
        a[ks] = *(const short8*)((const char*)sA + ((lin + (ks << 6)) ^ swz));
    }
    #pragma unroll
    for (int nf = 0; nf < 4; ++nf) {
      int brow = (nf << 4) + colsel;
      int lin = (brow << 8) + (kg << 4);
      int swz = (brow & 7) << 4;
      #pragma unroll
      for (int ks = 0; ks < 4; ++ks) {
        short8 b = *(const short8*)((const char*)sB + ((lin + (ks << 6)) ^ swz));
        acc[nf] = __builtin_amdgcn_mfma_f32_16x16x32_bf16(a[ks], b, acc[nf], 0, 0, 0);
      }
    }
  }
  const int r4 = kg << 2;
  #pragma unroll
  for (int nf = 0; nf < 4; ++nf) {
    int gn = n0 + (nf << 4) + colsel;
    #pragma unroll
    for (int reg = 0; reg < 4; ++reg) {
      int gm = m0 + wr + r4 + reg;
      atomicAdd(&out[(size_t)gm * 128 + gn], acc[nf][reg]);
    }
  }
}

// ---- in-LDS sel->abc transform (wave-synchronous; CL=16 rows, 4 waves) -----
__device__ __forceinline__ void transform_sbuf(float* sbuf, float a_d, int t) {
  const int d = t & 63;
  #pragma unroll
  for (int i = 0; i < 4; ++i) {
    float* R = sbuf + ((t >> 6) + i * 4) * 192;
    float draw = R[128];
    float sp = (draw > 15.f) ? draw : log1pf(__expf(draw));
    float delta = 0.01f * sp;
    R[d] = delta * R[d];
    R[128 + d] = __expf(delta * a_d);
  }
}

// ============================================================================
// Chunked scan (3 phases), CL=16, NTC=32. lane = m, all 64 d in registers.
// sbuf after transform: B_bar=[0:64], C=[64:128], A_bar=[128:192].
// cst: [b][tc<31][d][1024m] ; Ach: [b][tc<31][d]
// ============================================================================
__global__ __launch_bounds__(256)
void scan_sum(const ushort* __restrict__ ubf, const float* __restrict__ sel,
              const float* __restrict__ A,
              float* __restrict__ cst, float* __restrict__ Ach) {
  __shared__ __align__(16) float sbuf[CL * 192];
  const int t = threadIdx.x, lane = t & 63, w = t >> 6;
  const int tc = blockIdx.x % NC1;
  const int mg = (blockIdx.x / NC1) & 3;
  const int b  = blockIdx.x / (NC1 * 4);
  const int r0 = b * 512 + tc * CL;

  const float a_d = A[t & 63];
  const float4* src = (const float4*)(sel + (size_t)r0 * 192);
  #pragma unroll
  for (int i = 0; i < 3; ++i)
    ((float4*)sbuf)[t + i * 256] = src[t + i * 256];
  __syncthreads();
  transform_sbuf(sbuf, a_d, t);
  __syncthreads();

  const int m = (mg * 4 + w) * 64 + lane;
  const ushort* ub = ubf + (size_t)r0 * 1024 + m;
  const bool doAp = (mg == 0 && w == 0);

  float2 h[32], ap[32];
  #pragma unroll
  for (int j = 0; j < 32; ++j) { h[j] = make_float2(0.f, 0.f); ap[j] = make_float2(1.f, 1.f); }

  float u0 = frombf(ub[0]);
  float u1 = frombf(ub[1024]);
  for (int s = 0; s < CL; ++s) {
    int sn = (s < CL - 3) ? s + 2 : CL - 1;
    float u2 = frombf(ub[(size_t)sn * 1024]);
    const float* L = sbuf + s * 192;
    #pragma unroll
    for (int jj = 0; jj < 16; ++jj) {
      float4 a4 = *(const float4*)&L[128 + 4 * jj];
      float4 b4 = *(const float4*)&L[4 * jj];
      h[2 * jj].x     = fmaf(h[2 * jj].x,     a4.x, b4.x * u0);
      h[2 * jj].y     = fmaf(h[2 * jj].y,     a4.y, b4.y * u0);
      h[2 * jj + 1].x = fmaf(h[2 * jj + 1].x, a4.z, b4.z * u0);
      h[2 * jj + 1].y = fmaf(h[2 * jj + 1].y, a4.w, b4.w * u0);
    }
    if (doAp) {
      #pragma unroll
      for (int jj = 0; jj < 16; ++jj) {
        float4 a4 = *(const float4*)&L[128 + 4 * jj];
        ap[2 * jj].x     *= a4.x;
        ap[2 * jj].y     *= a4.y;
        ap[2 * jj + 1].x *= a4.z;
        ap[2 * jj + 1].y *= a4.w;
      }
    }
    u0 = u1; u1 = u2;
  }

  size_t cbase = (((size_t)b * NC1 + tc) * 64) * 1024 + m;
  #pragma unroll
  for (int j = 0; j < 32; ++j) {
    cst[cbase + (size_t)(2 * j)     * 1024] = h[j].x;
    cst[cbase + (size_t)(2 * j + 1) * 1024] = h[j].y;
  }
  if (doAp && lane == 0) {
    float2* ad = (float2*)&Ach[((size_t)b * NC1 + tc) * 64];
    #pragma unroll
    for (int j = 0; j < 32; ++j) ad[j] = ap[j];
  }
}

__global__ __launch_bounds__(256)
void scan_comb(float* __restrict__ cst, const float* __restrict__ Ach) {
  int g = blockIdx.x * 256 + threadIdx.x;  // 0..262143
  int b = g >> 16;
  int rem = g & 65535;
  int d = rem >> 10;
  int m = rem & 1023;
  float h = 0.f;
  for (int t2 = 0; t2 < NC1; ++t2) {
    size_t idx = (((size_t)(b * NC1 + t2)) * 64 + d) * 1024 + m;
    h = fmaf(Ach[(b * NC1 + t2) * 64 + d], h, cst[idx]);
    cst[idx] = h;
  }
}

// ---- scan_out: emit y bf16; LN sums via LDS transpose + post-loop reduce ---
__global__ __launch_bounds__(256)
void scan_out(const ushort* __restrict__ ubf, const float* __restrict__ sel,
              const float* __restrict__ A, const float* __restrict__ cst,
              const float* __restrict__ Dp, ushort* __restrict__ ybf,
              float* __restrict__ sums) {
  __shared__ __align__(16) float sbuf[CL * 192];   // 12.3 KB
  __shared__ float y_lds[256 * 17];                // 17.4 KB, pad 17
  const int t = threadIdx.x, lane = t & 63, w = t >> 6;
  const int tc = blockIdx.x & 31;
  const int mg = (blockIdx.x >> 5) & 3;
  const int b  = blockIdx.x >> 7;
  const int r0 = b * 512 + tc * CL;

  const float a_d = A[t & 63];
  const float4* src = (const float4*)(sel + (size_t)r0 * 192);
  #pragma unroll
  for (int i = 0; i < 3; ++i)
    ((float4*)sbuf)[t + i * 256] = src[t + i * 256];
  __syncthreads();
  transform_sbuf(sbuf, a_d, t);
  __syncthreads();

  const int m = (mg * 4 + w) * 64 + lane;
  const ushort* ub = ubf + (size_t)r0 * 1024 + m;
  ushort* yb = ybf + (size_t)r0 * 1024 + m;
  const float dp = Dp[m];

  float2 h[32];
  if (tc == 0) {
    #pragma unroll
    for (int j = 0; j < 32; ++j) h[j] = make_float2(0.f, 0.f);
  } else {
    size_t cbase = (((size_t)b * NC1 + (tc - 1)) * 64) * 1024 + m;
    #pragma unroll
    for (int j = 0; j < 32; ++j) {
      h[j].x = cst[cbase + (size_t)(2 * j)     * 1024];
      h[j].y = cst[cbase + (size_t)(2 * j + 1) * 1024];
    }
  }

  float u0 = frombf(ub[0]);
  float u1 = frombf(ub[1024]);
  for (int s = 0; s < CL; ++s) {
    int sn = (s < CL - 3) ? s + 2 : CL - 1;
    float u2 = frombf(ub[(size_t)sn * 1024]);
    const float* L = sbuf + s * 192;
    float y0 = 0.f, y1 = 0.f, y2 = 0.f, y3 = 0.f;
    #pragma unroll
    for (int jj = 0; jj < 16; ++jj) {
      float4 a4 = *(const float4*)&L[128 + 4 * jj];
      float4 b4 = *(const float4*)&L[4 * jj];
      float4 c4 = *(const float4*)&L[64 + 4 * jj];
      h[2 * jj].x     = fmaf(h[2 * jj].x,     a4.x, b4.x * u0);
      h[2 * jj].y     = fmaf(h[2 * jj].y,     a4.y, b4.y * u0);
      h[2 * jj + 1].x = fmaf(h[2 * jj + 1].x, a4.z, b4.z * u0);
      h[2 * jj + 1].y = fmaf(h[2 * jj + 1].y, a4.w, b4.w * u0);
      y0 = fmaf(c4.x, h[2 * jj].x,     y0);
      y1 = fmaf(c4.y, h[2 * jj].y,     y1);
      y2 = fmaf(c4.z, h[2 * jj + 1].x, y2);
      y3 = fmaf(c4.w, h[2 * jj + 1].y, y3);
    }
    float yv = (y0 + y1) + (y2 + y3) + u0 * dp;
    yb[(size_t)s * 1024] = tobf(yv);
    y_lds[t * 17 + s] = yv;                  // conflict-free (stride 17)
    u0 = u1; u1 = u2;
  }
  __syncthreads();
  // wave w reduces rows s = 4w..4w+3 over 256 m_local (off critical path)
  #pragma unroll
  for (int rr = 0; rr < 4; ++rr) {
    int s = w * 4 + rr;
    float s1 = 0.f, s2 = 0.f;
    #pragma unroll
    for (int i = 0; i < 4; ++i) {
      float v = y_lds[(i * 64 + lane) * 17 + s];  // lane stride 17: no conflict
      s1 += v; s2 += v * v;
    }
    #pragma unroll
    for (int o = 32; o; o >>= 1) {
      s1 += __shfl_xor(s1, o, 64);
      s2 += __shfl_xor(s2, o, 64);
    }
    if (lane == 0) {
      atomicAdd(&sums[r0 + s], s1);
      atomicAdd(&sums[2048 + r0 + s], s2);
    }
  }
}

extern "C" void kernel_launch(void* const* d_in, const int* in_sizes, int n_in,
                              void* d_out, int out_size, void* d_ws, size_t ws_size,
                              hipStream_t stream) {
  const float* x     = (const float*)d_in[0];
  const float* Wemb  = (const float*)d_in[1];
  const float* bemb  = (const float*)d_in[2];
  const float* Wxp   = (const float*)d_in[3];
  const float* bxp   = (const float*)d_in[4];
  const float* A     = (const float*)d_in[5];
  const float* Dp    = (const float*)d_in[6];
  const float* gamma = (const float*)d_in[7];
  const float* beta  = (const float*)d_in[8];
  const float* Wout  = (const float*)d_in[9];
  const float* bout  = (const float*)d_in[10];
  float* out = (float*)d_out;
  float* ws  = (float*)d_ws;

  // ws layout (floats)
  float* sel  = ws;                         //   393,216
  float* cst  = ws + 393216;                // 8,126,464 (4*31*64*1024)
  float* Ach  = ws + 8519680;               //     8,192 (7936 used)
  float* sums = ws + 8527872;               //     4,096 (s1|s2)
  ushort* ubf   = (ushort*)(ws + 8531968);  // 2,097,152 us
  ushort* ybf   = ubf + 2097152;            // 2,097,152 us
  ushort* xbf   = ybf + 2097152;            //   262,144 us
  ushort* WembT = xbf + 262144;             //   131,072 us
  ushort* wBCdT = WembT + 131072;           //   196,608 us
  ushort* WoutT = wBCdT + 196608;           //   131,072 us

  // P0: prep (transposes + x cast + sel/sums/out init)
  prep<<<5392, 256, 0, stream>>>(Wemb, Wxp, Wout, x, bxp, bout,
                                 WembT, wBCdT, WoutT, xbf, sel, sums, out);
  // P1: G1  ubf = bf16(x @ Wemb + bemb)
  gemm_bt<0><<<dim3(16, 32, 1), 256, 0, stream>>>(
      xbf, WembT, bemb, nullptr, ubf, 2048, 1024, 128, 0);
  // P2: G2  sel += ubf @ wBCdT^T  (split-K=4, atomics)
  gemm_bt<1><<<dim3(3, 32, 4), 256, 0, stream>>>(
      ubf, wBCdT, nullptr, sel, nullptr, 2048, 192, 1024, 256);
  // P3-P5: chunked scan (CL=16, 2 blocks/CU); scan_out emits bf16 y + LN sums
  scan_sum<<<4 * NC1 * 4, 256, 0, stream>>>(ubf, sel, A, cst, Ach);
  scan_comb<<<1024, 256, 0, stream>>>(cst, Ach);
  scan_out<<<512, 256, 0, stream>>>(ubf, sel, A, cst, Dp, ybf, sums);
  // P6: G4 with inline LN  out += LN(y) @ WoutT^T  (split-K=4, atomics)
  gemm_ln<<<dim3(2, 32, 4), 256, 0, stream>>>(
      ybf, WoutT, sums, gamma, beta, out);
}